// Round 13
// baseline (102.012 us; speedup 1.0000x reference)
//
#include <hip/hip_runtime.h>
#include <math.h>

#define BATCH 4096
#define DIM 128
#define NCLS 100
#define MARGIN 0.3f
#define NTILE 272          // upper-triangle 128x256 supertiles
#define GRID_ALL 272
#define MAGIC 0x13572468u

typedef __attribute__((ext_vector_type(8))) short short8;
typedef __attribute__((ext_vector_type(4))) float f32x4;

// ---- bf16 helpers (bit-level, RNE) ----
__device__ __forceinline__ unsigned short f2bf(float f) {
    unsigned int u = __float_as_uint(f);
    unsigned int r = (u + 0x7FFFu + ((u >> 16) & 1u)) >> 16;
    return (unsigned short)r;
}
__device__ __forceinline__ float bf2f(unsigned short b) {
    return __uint_as_float(((unsigned int)b) << 16);
}

// Order-preserving encodings for NONNEGATIVE floats; identity = 0 under atomic max.
#define ENC_MAX_ID 0x80000000u   /* enc_max(0.0f) */
#define ENC_MIN_ID 0x403FFFFFu   /* enc_min(+inf) */
__device__ __forceinline__ unsigned int enc_max(float v) {
    return (__float_as_uint(v) >> 1) | 0x80000000u;
}
__device__ __forceinline__ float dec_max(unsigned int k) {
    return __uint_as_float((k & 0x7FFFFFFFu) << 1);
}
__device__ __forceinline__ unsigned int enc_min(float v) {
    return 0x7FFFFFFFu - (__float_as_uint(v) >> 1);
}
__device__ __forceinline__ float dec_min(unsigned int k) {
    return __uint_as_float((0x7FFFFFFFu - k) << 1);
}

__device__ __forceinline__ void st_u32(unsigned int* p, unsigned int v) {
    __hip_atomic_store(p, v, __ATOMIC_RELAXED, __HIP_MEMORY_SCOPE_AGENT);
}

// convert 8 consecutive fp32 -> bf16x8 (RNE), accumulate sum of squares of
// the ROUNDED values (so diagonal d^2 == 0 exactly).
__device__ __forceinline__ short8 cvt8(const float* __restrict__ p, float& ss) {
    float4 x = *reinterpret_cast<const float4*>(p);
    float4 y = *reinterpret_cast<const float4*>(p + 4);
    unsigned short h0 = f2bf(x.x), h1 = f2bf(x.y), h2 = f2bf(x.z), h3 = f2bf(x.w);
    unsigned short h4 = f2bf(y.x), h5 = f2bf(y.y), h6 = f2bf(y.z), h7 = f2bf(y.w);
    float r0 = bf2f(h0), r1 = bf2f(h1), r2 = bf2f(h2), r3 = bf2f(h3);
    float r4 = bf2f(h4), r5 = bf2f(h5), r6 = bf2f(h6), r7 = bf2f(h7);
    ss += r0 * r0 + r1 * r1 + r2 * r2 + r3 * r3 + r4 * r4 + r5 * r5 + r6 * r6 + r7 * r7;
    short8 o;
    o[0] = (short)h0; o[1] = (short)h1; o[2] = (short)h2; o[3] = (short)h3;
    o[4] = (short)h4; o[5] = (short)h5; o[6] = (short)h6; o[7] = (short)h7;
    return o;
}

// SELF-CONTAINED single kernel: every block converts its own fp32 data.
// Block 0 additionally zeroes the fan region first and sets a set-once flag;
// all blocks gate their global publishes on the flag (never actually spins:
// zeroing ~1us << compute ~20us; flag stays set => no co-residency needed).
// blocks 0..271: upper-triangle 128x256 pairwise supertile (LDS B staging,
//                fp32->bf16 conversion fused into staging).
// blocks 0..255: + CE for rows bid*16.. via local fcw conversion in LDS.
// Tail: fence-free ticket fan-in; last block reduces + writes out[0].
__global__ __launch_bounds__(256, 2) void fused_kernel(
        const float* __restrict__ emb, const int* __restrict__ labels,
        const float* __restrict__ fcw, const float* __restrict__ fcb,
        float* __restrict__ out,
        unsigned int* __restrict__ maxk, unsigned int* __restrict__ mink,
        float* __restrict__ ce_sum, int* __restrict__ ticket,
        unsigned int* __restrict__ flag, unsigned int* __restrict__ fanz) {
    __shared__ float lg[16][128];                 // 8KB (CE logits + final red)
    __shared__ unsigned int colk[512];            // 2KB
    __shared__ unsigned short bstage[2][2048];    // 8KB (2 x 4KB B-tiles)
    __shared__ unsigned short wlds[7 * 2048];     // 28KB (fcw frag-major)
    __shared__ float sqpart[2][4][16];            // per-tile col-sq partials
    __shared__ float sqrowL[4][2][16];            // per-wave row sq
    __shared__ int lastFlag;
    int bid = blockIdx.x, tid = threadIdx.x;
    int wave = tid >> 6, lane = tid & 63;
    int lm = lane & 15, lq = lane >> 4;

    // ---- block 0: zero fan region (agent-scope; small), set set-once flag ----
    if (bid == 0) {
        for (int w = tid; w < 8194; w += 256) st_u32(&fanz[w], 0u);
        asm volatile("s_waitcnt vmcnt(0)" ::: "memory");
        __syncthreads();
        if (tid == 0) st_u32(flag, MAGIC);
    }

    // ---- triangle map: chunk c admits rowgrps 0..2c+1 ----
    int c = 0, rem = bid;
    while (rem >= 2 * c + 2) { rem -= 2 * c + 2; ++c; }
    int rowgrp = rem, chunk = c;
    int rbase = rowgrp * 128 + wave * 32;
    int cbase = chunk * 256;

    // ---- A: convert 2 row-groups straight into register fragments ----
    short8 afr[2][4];
    #pragma unroll
    for (int g = 0; g < 2; ++g) {
        int row = rbase + g * 16 + lm;
        const float* base = emb + row * DIM + lq * 8;
        float ss = 0.f;
        #pragma unroll
        for (int j = 0; j < 4; ++j) afr[g][j] = cvt8(base + j * 32, ss);
        ss += __shfl_xor(ss, 16, 64);
        ss += __shfl_xor(ss, 32, 64);      // full row sq in all lanes (per lm)
        if (lq == 0) sqrowL[wave][g][lm] = ss;
    }

    int labr[8];
    #pragma unroll
    for (int g = 0; g < 2; ++g)
        #pragma unroll
        for (int r = 0; r < 4; ++r)
            labr[g * 4 + r] = labels[rbase + g * 16 + lq * 4 + r];

    colk[tid] = 0; colk[256 + tid] = 0;
    __syncthreads();                       // sqrowL + colk visible

    float sqr[8];
    #pragma unroll
    for (int g = 0; g < 2; ++g)
        #pragma unroll
        for (int r = 0; r < 4; ++r)
            sqr[g * 4 + r] = sqrowL[wave][g][lq * 4 + r];

    float rmax[8], rmin[8];
    #pragma unroll
    for (int r = 0; r < 8; ++r) { rmax[r] = -INFINITY; rmin[r] = INFINITY; }

    // ---- B staging: convert fp32 -> bf16 into LDS, double-buffered ----
    int s = wave * 512 + lane * 8;         // short index within a 4KB tile
    int bc = s >> 7;                       // dim-chunk (0..15)
    int browl = (s >> 3) & 15;             // row within 16-col tile
    const float* bsrc0 = emb + (cbase + browl) * DIM + bc * 8;

    for (int ct = 0; ct < 16; ++ct) {
        float ssb = 0.f;
        short8 bq = cvt8(bsrc0 + ct * 16 * DIM, ssb);
        *reinterpret_cast<short8*>(&bstage[ct & 1][s]) = bq;
        ssb += __shfl_xor(ssb, 16, 64);
        ssb += __shfl_xor(ssb, 32, 64);    // sum over this wave's 4 chunks
        if (lq == 0) sqpart[ct & 1][wave][lm] = ssb;
        __syncthreads();

        const unsigned short* bb = &bstage[ct & 1][lane * 8];
        short8 b0 = *reinterpret_cast<const short8*>(bb);
        short8 b1 = *reinterpret_cast<const short8*>(bb + 512);
        short8 b2 = *reinterpret_cast<const short8*>(bb + 1024);
        short8 b3 = *reinterpret_cast<const short8*>(bb + 1536);
        f32x4 c0 = {0.f, 0.f, 0.f, 0.f};
        f32x4 c1 = {0.f, 0.f, 0.f, 0.f};
        c0 = __builtin_amdgcn_mfma_f32_16x16x32_bf16(afr[0][0], b0, c0, 0, 0, 0);
        c1 = __builtin_amdgcn_mfma_f32_16x16x32_bf16(afr[1][0], b0, c1, 0, 0, 0);
        c0 = __builtin_amdgcn_mfma_f32_16x16x32_bf16(afr[0][1], b1, c0, 0, 0, 0);
        c1 = __builtin_amdgcn_mfma_f32_16x16x32_bf16(afr[1][1], b1, c1, 0, 0, 0);
        c0 = __builtin_amdgcn_mfma_f32_16x16x32_bf16(afr[0][2], b2, c0, 0, 0, 0);
        c1 = __builtin_amdgcn_mfma_f32_16x16x32_bf16(afr[1][2], b2, c1, 0, 0, 0);
        c0 = __builtin_amdgcn_mfma_f32_16x16x32_bf16(afr[0][3], b3, c0, 0, 0, 0);
        c1 = __builtin_amdgcn_mfma_f32_16x16x32_bf16(afr[1][3], b3, c1, 0, 0, 0);

        int col = cbase + ct * 16 + lm;
        float sqc = sqpart[ct & 1][0][lm] + sqpart[ct & 1][1][lm]
                  + sqpart[ct & 1][2][lm] + sqpart[ct & 1][3][lm];
        int lc = labels[col];
        float cmax = -INFINITY, cmin = INFINITY;
        #pragma unroll
        for (int r = 0; r < 4; ++r) {
            float v0 = fmaxf(fmaf(c0[r], -2.0f, sqc) + sqr[r], 0.f);
            bool s0 = (lc == labr[r]);
            rmax[r] = s0 ? fmaxf(rmax[r], v0) : rmax[r];
            rmin[r] = s0 ? rmin[r] : fminf(rmin[r], v0);
            cmax    = s0 ? fmaxf(cmax, v0) : cmax;
            cmin    = s0 ? cmin : fminf(cmin, v0);
            float v1 = fmaxf(fmaf(c1[r], -2.0f, sqc) + sqr[4 + r], 0.f);
            bool s1 = (lc == labr[4 + r]);
            rmax[4 + r] = s1 ? fmaxf(rmax[4 + r], v1) : rmax[4 + r];
            rmin[4 + r] = s1 ? rmin[4 + r] : fminf(rmin[4 + r], v1);
            cmax        = s1 ? fmaxf(cmax, v1) : cmax;
            cmin        = s1 ? cmin : fminf(cmin, v1);
        }
        cmax = fmaxf(cmax, __shfl_xor(cmax, 16, 64));
        cmax = fmaxf(cmax, __shfl_xor(cmax, 32, 64));
        cmin = fminf(cmin, __shfl_xor(cmin, 16, 64));
        cmin = fminf(cmin, __shfl_xor(cmin, 32, 64));
        if (lq == 0) {
            atomicMax(&colk[ct * 16 + lm], enc_max(fmaxf(cmax, 0.f)));
            atomicMax(&colk[256 + ct * 16 + lm], enc_min(fmaxf(cmin, 0.f)));
        }
    }
    // row reduce across the 16 col-slots
    #pragma unroll
    for (int off = 1; off < 16; off <<= 1) {
        #pragma unroll
        for (int r = 0; r < 8; ++r) {
            rmax[r] = fmaxf(rmax[r], __shfl_xor(rmax[r], off, 64));
            rmin[r] = fminf(rmin[r], __shfl_xor(rmin[r], off, 64));
        }
    }

    // ---- gate publishes on the set-once flag (never actually spins) ----
    if (tid == 0) {
        while (__hip_atomic_load(flag, __ATOMIC_RELAXED,
                                 __HIP_MEMORY_SCOPE_AGENT) != MAGIC)
            __builtin_amdgcn_s_sleep(2);
    }
    __syncthreads();

    if (lm == 0) {
        #pragma unroll
        for (int g = 0; g < 2; ++g)
            #pragma unroll
            for (int r = 0; r < 4; ++r) {
                int row = rbase + g * 16 + lq * 4 + r;
                unsigned int kx = enc_max(fmaxf(rmax[g * 4 + r], 0.f));
                unsigned int kn = enc_min(fmaxf(rmin[g * 4 + r], 0.f));
                if (kx != ENC_MAX_ID)
                    __hip_atomic_fetch_max(&maxk[row], kx,
                                           __ATOMIC_RELAXED, __HIP_MEMORY_SCOPE_AGENT);
                if (kn != ENC_MIN_ID)
                    __hip_atomic_fetch_max(&mink[row], kn,
                                           __ATOMIC_RELAXED, __HIP_MEMORY_SCOPE_AGENT);
            }
    }
    __syncthreads();
    {
        unsigned int kx = colk[tid], kn = colk[256 + tid];
        int col = cbase + tid;
        if (kx > ENC_MAX_ID)
            __hip_atomic_fetch_max(&maxk[col], kx,
                                   __ATOMIC_RELAXED, __HIP_MEMORY_SCOPE_AGENT);
        if (kn != 0 && kn != ENC_MIN_ID)
            __hip_atomic_fetch_max(&mink[col], kn,
                                   __ATOMIC_RELAXED, __HIP_MEMORY_SCOPE_AGENT);
    }

    // ---------------- CE (blocks 0..255), fully local ----------------
    if (bid < 256) {
        int R0 = bid * 16;
        // convert fcw -> wlds (frag-major, padded to 112 classes)
        unsigned int* w32 = reinterpret_cast<unsigned int*>(wlds);
        for (int t = tid; t < 7168; t += 256) {
            int k = t * 2;
            int cls = k >> 7, d = k & 127;
            unsigned int packed = 0;
            if (k < NCLS * DIM)
                packed = ((unsigned int)f2bf(fcw[k + 1]) << 16) | (unsigned int)f2bf(fcw[k]);
            int dst = (cls >> 4) * 2048 + (d >> 3) * 128 + (cls & 15) * 8 + (d & 7);
            w32[dst >> 1] = packed;
        }
        // CE A-frags for rows R0..R0+15, converted directly from fp32
        float dummy = 0.f;
        const float* base = emb + (R0 + lm) * DIM + lq * 8;
        short8 ca0 = cvt8(base, dummy);
        short8 ca1 = cvt8(base + 32, dummy);
        short8 ca2 = cvt8(base + 64, dummy);
        short8 ca3 = cvt8(base + 96, dummy);
        lg[tid >> 4][112 + (tid & 15)] = -INFINITY;
        __syncthreads();

        for (int t = wave * 2; t < 7 && t < wave * 2 + 2; ++t) {
            int cls = t * 16 + lm;
            const unsigned short* bp = wlds + t * 2048 + lane * 8;
            short8 b0 = *reinterpret_cast<const short8*>(bp);
            short8 b1 = *reinterpret_cast<const short8*>(bp + 512);
            short8 b2 = *reinterpret_cast<const short8*>(bp + 1024);
            short8 b3 = *reinterpret_cast<const short8*>(bp + 1536);
            f32x4 cc = {0.f, 0.f, 0.f, 0.f};
            cc = __builtin_amdgcn_mfma_f32_16x16x32_bf16(ca0, b0, cc, 0, 0, 0);
            cc = __builtin_amdgcn_mfma_f32_16x16x32_bf16(ca1, b1, cc, 0, 0, 0);
            cc = __builtin_amdgcn_mfma_f32_16x16x32_bf16(ca2, b2, cc, 0, 0, 0);
            cc = __builtin_amdgcn_mfma_f32_16x16x32_bf16(ca3, b3, cc, 0, 0, 0);
            float bias = (cls < NCLS) ? fcb[cls] : -INFINITY;
            #pragma unroll
            for (int r = 0; r < 4; ++r)
                lg[lq * 4 + r][t * 16 + lm] = cc[r] + bias;
        }
        __syncthreads();
        float cacc = 0.f;
        #pragma unroll
        for (int i = 0; i < 4; ++i) {
            int r = wave * 4 + i;
            float x0 = lg[r][lane], x1 = lg[r][lane + 64];
            float m = fmaxf(x0, x1);
            #pragma unroll
            for (int off = 1; off < 64; off <<= 1) m = fmaxf(m, __shfl_xor(m, off, 64));
            float ssum = expf(x0 - m) + expf(x1 - m);
            #pragma unroll
            for (int off = 1; off < 64; off <<= 1) ssum += __shfl_xor(ssum, off, 64);
            if (lane == 0) {
                int lab = labels[R0 + r];
                cacc += (m + logf(ssum)) - lg[r][lab];
            }
        }
        __syncthreads();
        if (lane == 0) lg[0][wave] = cacc;
        __syncthreads();
        if (tid == 0) {
            float bsum = lg[0][0] + lg[0][1] + lg[0][2] + lg[0][3];
            __hip_atomic_fetch_add(ce_sum, bsum,
                                   __ATOMIC_RELAXED, __HIP_MEMORY_SCOPE_AGENT);
        }
    }

    // ---------------- fence-free final ticket fan-in ----------------
    __syncthreads();
    asm volatile("s_waitcnt vmcnt(0)" ::: "memory");
    if (tid == 0) {
        int old = __hip_atomic_fetch_add(ticket, 1,
                                         __ATOMIC_RELAXED, __HIP_MEMORY_SCOPE_AGENT);
        lastFlag = (old == GRID_ALL - 1);
    }
    __syncthreads();
    if (lastFlag) {
        float acc = 0.f;
        #pragma unroll
        for (int rr = 0; rr < 16; ++rr) {
            int row = rr * 256 + tid;
            unsigned int kx = __hip_atomic_load(&maxk[row], __ATOMIC_RELAXED,
                                                __HIP_MEMORY_SCOPE_AGENT);
            unsigned int kn = __hip_atomic_load(&mink[row], __ATOMIC_RELAXED,
                                                __HIP_MEMORY_SCOPE_AGENT);
            float ap = sqrtf(fmaxf(dec_max(kx), 1e-12f));
            float an = sqrtf(fmaxf(dec_min(kn), 1e-12f));
            acc += fmaxf(ap - an + MARGIN, 0.f);
        }
        float* red = reinterpret_cast<float*>(lg);
        red[tid] = acc;
        __syncthreads();
        for (int st = 128; st > 0; st >>= 1) {
            if (tid < st) red[tid] += red[tid + st];
            __syncthreads();
        }
        if (tid == 0) {
            float ces = __hip_atomic_load(ce_sum, __ATOMIC_RELAXED,
                                          __HIP_MEMORY_SCOPE_AGENT);
            out[0] = (red[0] + ces) * (1.0f / BATCH);
        }
    }
}

extern "C" void kernel_launch(void* const* d_in, const int* in_sizes, int n_in,
                              void* d_out, int out_size, void* d_ws, size_t ws_size,
                              hipStream_t stream) {
    const float* emb    = (const float*)d_in[0];
    const int*   labels = (const int*)  d_in[1];
    const float* fcw    = (const float*)d_in[2];
    const float* fcb    = (const float*)d_in[3];
    float* out = (float*)d_out;

    char* fan = (char*)d_ws;                       // zeroed by block 0 in-kernel
    int*   ticket       = (int*)(fan);             // word 0
    float* ce_sum       = (float*)(fan + 4);       // word 1
    unsigned int* maxk  = (unsigned int*)(fan + 8);            // 4096 words
    unsigned int* mink  = (unsigned int*)(fan + 8 + 16384);    // 4096 words
    unsigned int* flag  = (unsigned int*)(fan + 8 + 32768);    // word 8194 (NOT zeroed)

    fused_kernel<<<GRID_ALL, 256, 0, stream>>>(
        emb, labels, fcw, fcb, out, maxk, mink, ce_sum, ticket, flag,
        (unsigned int*)fan);
}

// Round 14
// 96.385 us; speedup vs baseline: 1.0584x; 1.0584x over previous
//
#include <hip/hip_runtime.h>
#include <math.h>

#define BATCH 4096
#define DIM 128
#define NCLS 100
#define MARGIN 0.3f
#define GRID_MAIN 512      // 256 pairwise (full-matrix, balanced) + 256 CE

typedef __attribute__((ext_vector_type(8))) short short8;
typedef __attribute__((ext_vector_type(4))) float f32x4;

// ---- bf16 helpers (bit-level, RNE) ----
__device__ __forceinline__ unsigned short f2bf(float f) {
    unsigned int u = __float_as_uint(f);
    unsigned int r = (u + 0x7FFFu + ((u >> 16) & 1u)) >> 16;
    return (unsigned short)r;
}
__device__ __forceinline__ float bf2f(unsigned short b) {
    return __uint_as_float(((unsigned int)b) << 16);
}

// Order-preserving encodings for NONNEGATIVE floats; identity = 0 under atomic max.
#define ENC_MAX_ID 0x80000000u   /* enc_max(0.0f) */
#define ENC_MIN_ID 0x403FFFFFu   /* enc_min(+inf) */
__device__ __forceinline__ unsigned int enc_max(float v) {
    return (__float_as_uint(v) >> 1) | 0x80000000u;
}
__device__ __forceinline__ float dec_max(unsigned int k) {
    return __uint_as_float((k & 0x7FFFFFFFu) << 1);
}
__device__ __forceinline__ unsigned int enc_min(float v) {
    return 0x7FFFFFFFu - (__float_as_uint(v) >> 1);
}
__device__ __forceinline__ float dec_min(unsigned int k) {
    return __uint_as_float((0x7FFFFFFFu - k) << 1);
}

// FRAGMENT-MAJOR layout: for 16-row group g, element (row%16, dim) lives at
// short-index g*2048 + (dim>>3)*128 + (row%16)*8 + (dim&7). Fragment read j
// for lane l is contiguous: g*2048 + j*512 + l*8 shorts = base + l*16 bytes.

// K1 (unchanged from R11): blocks 0..255 emb->bf16 frag-major + sq;
//     blocks 256..257 fc_w->bf16 frag-major + zero fan region.
__global__ __launch_bounds__(256) void prep_kernel(
        const float* __restrict__ emb, const float* __restrict__ fcw,
        unsigned short* __restrict__ ebf, float* __restrict__ sq,
        unsigned short* __restrict__ wbf, unsigned int* __restrict__ fanz) {
    int bid = blockIdx.x, tid = threadIdx.x;
    if (bid < 256) {
        int wave = tid >> 6, lane = tid & 63;
        unsigned int* dstg = reinterpret_cast<unsigned int*>(ebf) + bid * 1024;
        #pragma unroll
        for (int r = 0; r < 4; ++r) {
            int rowl = wave * 4 + r;
            int row = bid * 16 + rowl;
            const float2* src = reinterpret_cast<const float2*>(emb + row * DIM);
            float2 xy = src[lane];
            unsigned short b0 = f2bf(xy.x), b1 = f2bf(xy.y);
            float y0 = bf2f(b0), y1 = bf2f(b1);
            dstg[(lane >> 2) * 64 + rowl * 4 + (lane & 3)] =
                ((unsigned int)b1 << 16) | (unsigned int)b0;
            float acc = y0 * y0 + y1 * y1;
            #pragma unroll
            for (int off = 1; off < 64; off <<= 1) acc += __shfl_xor(acc, off, 64);
            if (lane == 0) sq[row] = acc;
        }
    } else {
        int idx = (bid - 256) * 256 + tid;          // 512 threads total
        for (int k = idx; k < 112 * DIM; k += 512) {
            int cls = k >> 7, d = k & 127;
            int dst = (cls >> 4) * 2048 + (d >> 3) * 128 + (cls & 15) * 8 + (d & 7);
            wbf[dst] = (k < NCLS * DIM) ? f2bf(fcw[k]) : (unsigned short)0;
        }
        for (int w = idx; w < 8194; w += 512)       // ticket+ce_sum+maxk+mink
            fanz[w] = 0;
    }
}

// K2: blocks 0..255  -> FULL-MATRIX 128x512 pairwise tiles, exactly 1/CU
//                       (no tail imbalance, no col-side merges needed);
//                       LDS double-buffered B staging, row-only atomic publish.
//     blocks 256..511 -> CE per 16 rows via MFMA logits + wave softmax.
//     Fence-free ticket fan-in; last block reduces + writes out[0].
__global__ __launch_bounds__(256) void main_kernel(
        const unsigned short* __restrict__ ebf, const unsigned short* __restrict__ wbf,
        const float* __restrict__ sq, const int* __restrict__ labels,
        const float* __restrict__ fcb,
        unsigned int* __restrict__ maxk, unsigned int* __restrict__ mink,
        float* __restrict__ ce_sum, int* __restrict__ ticket,
        float* __restrict__ out) {
    __shared__ float lg[16][128];
    __shared__ unsigned short bstage[2][2048];   // 2 x 4KB B-tiles
    __shared__ int lastFlag;
    int bid = blockIdx.x, tid = threadIdx.x;
    int wave = tid >> 6, lane = tid & 63;
    int lm = lane & 15, lq = lane >> 4;

    if (bid < 256) {
        // ---- full-matrix map: 32 rowgrps x 8 chunks -> exactly 256 blocks ----
        int rowgrp = bid >> 3, chunk = bid & 7;

        int rbase = rowgrp * 128 + wave * 32;   // this wave's 32 rows
        const unsigned short* apt = ebf + (rbase >> 4) * 2048 + lane * 8;
        short8 a0 = *reinterpret_cast<const short8*>(apt);
        short8 a1 = *reinterpret_cast<const short8*>(apt + 512);
        short8 a2 = *reinterpret_cast<const short8*>(apt + 1024);
        short8 a3 = *reinterpret_cast<const short8*>(apt + 1536);
        short8 a4 = *reinterpret_cast<const short8*>(apt + 2048);
        short8 a5 = *reinterpret_cast<const short8*>(apt + 2560);
        short8 a6 = *reinterpret_cast<const short8*>(apt + 3072);
        short8 a7 = *reinterpret_cast<const short8*>(apt + 3584);

        int labr[8];
        float sqr[8];
        #pragma unroll
        for (int g = 0; g < 2; ++g)
            #pragma unroll
            for (int r = 0; r < 4; ++r) {
                labr[g * 4 + r] = labels[rbase + g * 16 + lq * 4 + r];
                sqr[g * 4 + r]  = sq[rbase + g * 16 + lq * 4 + r];
            }

        float rmax[8], rmin[8];
        #pragma unroll
        for (int r = 0; r < 8; ++r) { rmax[r] = -INFINITY; rmin[r] = INFINITY; }

        int cbase = chunk * 512;               // 512 cols per block
        const unsigned short* btile = ebf + (cbase >> 4) * 2048 + wave * 512 + lane * 8;
        uint4 breg = *reinterpret_cast<const uint4*>(btile);   // tile 0

        for (int ct = 0; ct < 32; ++ct) {
            *reinterpret_cast<uint4*>(&bstage[ct & 1][wave * 512 + lane * 8]) = breg;
            if (ct < 31)
                breg = *reinterpret_cast<const uint4*>(btile + (ct + 1) * 2048);
            __syncthreads();

            const unsigned short* bb = &bstage[ct & 1][lane * 8];
            short8 b0 = *reinterpret_cast<const short8*>(bb);
            short8 b1 = *reinterpret_cast<const short8*>(bb + 512);
            short8 b2 = *reinterpret_cast<const short8*>(bb + 1024);
            short8 b3 = *reinterpret_cast<const short8*>(bb + 1536);
            f32x4 c0 = {0.f, 0.f, 0.f, 0.f};
            f32x4 c1 = {0.f, 0.f, 0.f, 0.f};
            c0 = __builtin_amdgcn_mfma_f32_16x16x32_bf16(a0, b0, c0, 0, 0, 0);
            c1 = __builtin_amdgcn_mfma_f32_16x16x32_bf16(a4, b0, c1, 0, 0, 0);
            c0 = __builtin_amdgcn_mfma_f32_16x16x32_bf16(a1, b1, c0, 0, 0, 0);
            c1 = __builtin_amdgcn_mfma_f32_16x16x32_bf16(a5, b1, c1, 0, 0, 0);
            c0 = __builtin_amdgcn_mfma_f32_16x16x32_bf16(a2, b2, c0, 0, 0, 0);
            c1 = __builtin_amdgcn_mfma_f32_16x16x32_bf16(a6, b2, c1, 0, 0, 0);
            c0 = __builtin_amdgcn_mfma_f32_16x16x32_bf16(a3, b3, c0, 0, 0, 0);
            c1 = __builtin_amdgcn_mfma_f32_16x16x32_bf16(a7, b3, c1, 0, 0, 0);

            int col = cbase + ct * 16 + lm;
            float sqc = sq[col];
            int lc = labels[col];
            // row-only epilogue (full matrix => columns covered by their own rows)
            #pragma unroll
            for (int r = 0; r < 4; ++r) {
                float v0 = fmaxf(fmaf(c0[r], -2.0f, sqc) + sqr[r], 0.f);
                bool s0 = (lc == labr[r]);
                rmax[r] = s0 ? fmaxf(rmax[r], v0) : rmax[r];
                rmin[r] = s0 ? rmin[r] : fminf(rmin[r], v0);
                float v1 = fmaxf(fmaf(c1[r], -2.0f, sqc) + sqr[4 + r], 0.f);
                bool s1 = (lc == labr[4 + r]);
                rmax[4 + r] = s1 ? fmaxf(rmax[4 + r], v1) : rmax[4 + r];
                rmin[4 + r] = s1 ? rmin[4 + r] : fminf(rmin[4 + r], v1);
            }
        }
        // row reduce across the 16 col-slots
        #pragma unroll
        for (int off = 1; off < 16; off <<= 1) {
            #pragma unroll
            for (int r = 0; r < 8; ++r) {
                rmax[r] = fmaxf(rmax[r], __shfl_xor(rmax[r], off, 64));
                rmin[r] = fminf(rmin[r], __shfl_xor(rmin[r], off, 64));
            }
        }
        if (lm == 0) {
            #pragma unroll
            for (int g = 0; g < 2; ++g)
                #pragma unroll
                for (int r = 0; r < 4; ++r) {
                    int row = rbase + g * 16 + lq * 4 + r;
                    unsigned int kx = enc_max(fmaxf(rmax[g * 4 + r], 0.f));
                    unsigned int kn = enc_min(fmaxf(rmin[g * 4 + r], 0.f));
                    if (kx != ENC_MAX_ID)
                        __hip_atomic_fetch_max(&maxk[row], kx,
                                               __ATOMIC_RELAXED, __HIP_MEMORY_SCOPE_AGENT);
                    if (kn != ENC_MIN_ID)
                        __hip_atomic_fetch_max(&mink[row], kn,
                                               __ATOMIC_RELAXED, __HIP_MEMORY_SCOPE_AGENT);
                }
        }
    } else {
        // ---------------- cross-entropy ----------------
        int R0 = (bid - 256) * 16;
        lg[tid >> 4][112 + (tid & 15)] = -INFINITY;   // pad cols 112..127

        const unsigned short* apt = ebf + (R0 >> 4) * 2048 + lane * 8;
        short8 a0 = *reinterpret_cast<const short8*>(apt);
        short8 a1 = *reinterpret_cast<const short8*>(apt + 512);
        short8 a2 = *reinterpret_cast<const short8*>(apt + 1024);
        short8 a3 = *reinterpret_cast<const short8*>(apt + 1536);

        for (int t = wave * 2; t < 7 && t < wave * 2 + 2; ++t) {
            int cls = t * 16 + lm;
            const unsigned short* bp = wbf + t * 2048 + lane * 8;
            short8 b0 = *reinterpret_cast<const short8*>(bp);
            short8 b1 = *reinterpret_cast<const short8*>(bp + 512);
            short8 b2 = *reinterpret_cast<const short8*>(bp + 1024);
            short8 b3 = *reinterpret_cast<const short8*>(bp + 1536);
            f32x4 c = {0.f, 0.f, 0.f, 0.f};
            c = __builtin_amdgcn_mfma_f32_16x16x32_bf16(a0, b0, c, 0, 0, 0);
            c = __builtin_amdgcn_mfma_f32_16x16x32_bf16(a1, b1, c, 0, 0, 0);
            c = __builtin_amdgcn_mfma_f32_16x16x32_bf16(a2, b2, c, 0, 0, 0);
            c = __builtin_amdgcn_mfma_f32_16x16x32_bf16(a3, b3, c, 0, 0, 0);
            float bias = (cls < NCLS) ? fcb[cls] : -INFINITY;
            #pragma unroll
            for (int r = 0; r < 4; ++r)
                lg[lq * 4 + r][t * 16 + lm] = c[r] + bias;
        }
        __syncthreads();
        float cacc = 0.f;
        #pragma unroll
        for (int i = 0; i < 4; ++i) {
            int r = wave * 4 + i;
            float x0 = lg[r][lane], x1 = lg[r][lane + 64];
            float m = fmaxf(x0, x1);
            #pragma unroll
            for (int off = 1; off < 64; off <<= 1) m = fmaxf(m, __shfl_xor(m, off, 64));
            float s = expf(x0 - m) + expf(x1 - m);    // -inf pads -> 0
            #pragma unroll
            for (int off = 1; off < 64; off <<= 1) s += __shfl_xor(s, off, 64);
            if (lane == 0) {
                int lab = labels[R0 + r];
                cacc += (m + logf(s)) - lg[r][lab];
            }
        }
        __syncthreads();
        if (lane == 0) lg[0][wave] = cacc;
        __syncthreads();
        if (tid == 0) {
            float bsum = lg[0][0] + lg[0][1] + lg[0][2] + lg[0][3];
            __hip_atomic_fetch_add(ce_sum, bsum,
                                   __ATOMIC_RELAXED, __HIP_MEMORY_SCOPE_AGENT);
        }
    }

    // ------- fence-free ticket fan-in -------
    __syncthreads();
    asm volatile("s_waitcnt vmcnt(0)" ::: "memory");
    if (tid == 0) {
        int old = __hip_atomic_fetch_add(ticket, 1,
                                         __ATOMIC_RELAXED, __HIP_MEMORY_SCOPE_AGENT);
        lastFlag = (old == GRID_MAIN - 1);
    }
    __syncthreads();
    if (lastFlag) {
        float acc = 0.f;
        #pragma unroll
        for (int rr = 0; rr < 16; ++rr) {
            int row = rr * 256 + tid;
            unsigned int kx = __hip_atomic_load(&maxk[row], __ATOMIC_RELAXED,
                                                __HIP_MEMORY_SCOPE_AGENT);
            unsigned int kn = __hip_atomic_load(&mink[row], __ATOMIC_RELAXED,
                                                __HIP_MEMORY_SCOPE_AGENT);
            float ap = sqrtf(fmaxf(dec_max(kx), 1e-12f));
            float an = sqrtf(fmaxf(dec_min(kn), 1e-12f));
            acc += fmaxf(ap - an + MARGIN, 0.f);
        }
        float* red = reinterpret_cast<float*>(lg);
        red[tid] = acc;
        __syncthreads();
        for (int s = 128; s > 0; s >>= 1) {
            if (tid < s) red[tid] += red[tid + s];
            __syncthreads();
        }
        if (tid == 0) {
            float ces = __hip_atomic_load(ce_sum, __ATOMIC_RELAXED,
                                          __HIP_MEMORY_SCOPE_AGENT);
            out[0] = (red[0] + ces) * (1.0f / BATCH);
        }
    }
}

extern "C" void kernel_launch(void* const* d_in, const int* in_sizes, int n_in,
                              void* d_out, int out_size, void* d_ws, size_t ws_size,
                              hipStream_t stream) {
    const float* emb    = (const float*)d_in[0];
    const int*   labels = (const int*)  d_in[1];
    const float* fcw    = (const float*)d_in[2];
    const float* fcb    = (const float*)d_in[3];
    float* out = (float*)d_out;

    char* ws = (char*)d_ws;
    unsigned short* ebf = (unsigned short*)(ws);                 // 1 MB (frag-major)
    unsigned short* wbf = (unsigned short*)(ws + 1048576);       // 28 KB (pad 32K)
    float* sq           = (float*)(ws + 1081344);                // 16 KB
    char* fan           = ws + 1097728;                          // zeroed by prep
    int*   ticket       = (int*)(fan);                           // 4 B
    float* ce_sum       = (float*)(fan + 4);                     // 4 B
    unsigned int* maxk  = (unsigned int*)(fan + 8);              // 16 KB
    unsigned int* mink  = (unsigned int*)(fan + 8 + 16384);      // 16 KB

    prep_kernel<<<258, 256, 0, stream>>>(emb, fcw, ebf, sq, wbf,
                                         (unsigned int*)fan);
    main_kernel<<<GRID_MAIN, 256, 0, stream>>>(ebf, wbf, sq, labels, fcb,
                                               maxk, mink, ce_sum, ticket, out);
}

// Round 15
// 95.470 us; speedup vs baseline: 1.0685x; 1.0096x over previous
//
#include <hip/hip_runtime.h>
#include <math.h>

#define BATCH 4096
#define DIM 128
#define NCLS 100
#define MARGIN 0.3f
#define NTILE 272          // upper-triangle 128x256 supertiles
#define GRID_MAIN 272      // pairwise supertiles; blocks 0..255 also do CE

typedef __attribute__((ext_vector_type(8))) short short8;
typedef __attribute__((ext_vector_type(4))) float f32x4;

// ---- bf16 helpers (bit-level, RNE) ----
__device__ __forceinline__ unsigned short f2bf(float f) {
    unsigned int u = __float_as_uint(f);
    unsigned int r = (u + 0x7FFFu + ((u >> 16) & 1u)) >> 16;
    return (unsigned short)r;
}
__device__ __forceinline__ float bf2f(unsigned short b) {
    return __uint_as_float(((unsigned int)b) << 16);
}

// Order-preserving encodings for NONNEGATIVE floats; identity = 0 under atomic max.
#define ENC_MAX_ID 0x80000000u   /* enc_max(0.0f) */
#define ENC_MIN_ID 0x403FFFFFu   /* enc_min(+inf) */
__device__ __forceinline__ unsigned int enc_max(float v) {
    return (__float_as_uint(v) >> 1) | 0x80000000u;
}
__device__ __forceinline__ float dec_max(unsigned int k) {
    return __uint_as_float((k & 0x7FFFFFFFu) << 1);
}
__device__ __forceinline__ unsigned int enc_min(float v) {
    return 0x7FFFFFFFu - (__float_as_uint(v) >> 1);
}
__device__ __forceinline__ float dec_min(unsigned int k) {
    return __uint_as_float((0x7FFFFFFFu - k) << 1);
}

// FRAGMENT-MAJOR layout: for 16-row group g, element (row%16, dim) lives at
// short-index g*2048 + (dim>>3)*128 + (row%16)*8 + (dim&7). Fragment read j
// for lane l is contiguous: g*2048 + j*512 + l*8 shorts = base + l*16 bytes.

// K1 (unchanged): blocks 0..255 emb->bf16 frag-major + sq;
//     blocks 256..257 fc_w->bf16 frag-major + zero fan region.
__global__ __launch_bounds__(256) void prep_kernel(
        const float* __restrict__ emb, const float* __restrict__ fcw,
        unsigned short* __restrict__ ebf, float* __restrict__ sq,
        unsigned short* __restrict__ wbf, unsigned int* __restrict__ fanz) {
    int bid = blockIdx.x, tid = threadIdx.x;
    if (bid < 256) {
        int wave = tid >> 6, lane = tid & 63;
        unsigned int* dstg = reinterpret_cast<unsigned int*>(ebf) + bid * 1024;
        #pragma unroll
        for (int r = 0; r < 4; ++r) {
            int rowl = wave * 4 + r;
            int row = bid * 16 + rowl;
            const float2* src = reinterpret_cast<const float2*>(emb + row * DIM);
            float2 xy = src[lane];
            unsigned short b0 = f2bf(xy.x), b1 = f2bf(xy.y);
            float y0 = bf2f(b0), y1 = bf2f(b1);
            dstg[(lane >> 2) * 64 + rowl * 4 + (lane & 3)] =
                ((unsigned int)b1 << 16) | (unsigned int)b0;
            float acc = y0 * y0 + y1 * y1;
            #pragma unroll
            for (int off = 1; off < 64; off <<= 1) acc += __shfl_xor(acc, off, 64);
            if (lane == 0) sq[row] = acc;
        }
    } else {
        int idx = (bid - 256) * 256 + tid;          // 512 threads total
        for (int k = idx; k < 112 * DIM; k += 512) {
            int cls = k >> 7, d = k & 127;
            int dst = (cls >> 4) * 2048 + (d >> 3) * 128 + (cls & 15) * 8 + (d & 7);
            wbf[dst] = (k < NCLS * DIM) ? f2bf(fcw[k]) : (unsigned short)0;
        }
        for (int w = idx; w < 8194; w += 512)       // ticket+ce_sum+maxk+mink
            fanz[w] = 0;
    }
}

// K2: 272 blocks. Upper-triangle 128x256 supertile with TWO-TILE LDS staging
//     (8 loop barriers instead of 16; 2 prefetch loads in flight).
//     Blocks 0..255 then run CE for rows bid*16.. within the same block.
//     Fence-free ticket fan-in; last block reduces + writes out[0].
__global__ __launch_bounds__(256) void main_kernel(
        const unsigned short* __restrict__ ebf, const unsigned short* __restrict__ wbf,
        const float* __restrict__ sq, const int* __restrict__ labels,
        const float* __restrict__ fcb,
        unsigned int* __restrict__ maxk, unsigned int* __restrict__ mink,
        float* __restrict__ ce_sum, int* __restrict__ ticket,
        float* __restrict__ out) {
    __shared__ float lg[16][128];
    __shared__ unsigned int colk[512];
    __shared__ unsigned short bstage[2][4096];   // 2 x 8KB (two tiles per stage)
    __shared__ int lastFlag;
    int bid = blockIdx.x, tid = threadIdx.x;
    int wave = tid >> 6, lane = tid & 63;
    int lm = lane & 15, lq = lane >> 4;

    {
        // ---- triangle map: chunk c admits rowgrps 0..2c+1 ----
        int c = 0, rem = bid;
        while (rem >= 2 * c + 2) { rem -= 2 * c + 2; ++c; }
        int rowgrp = rem, chunk = c;

        int rbase = rowgrp * 128 + wave * 32;
        const unsigned short* apt = ebf + (rbase >> 4) * 2048 + lane * 8;
        short8 a0 = *reinterpret_cast<const short8*>(apt);
        short8 a1 = *reinterpret_cast<const short8*>(apt + 512);
        short8 a2 = *reinterpret_cast<const short8*>(apt + 1024);
        short8 a3 = *reinterpret_cast<const short8*>(apt + 1536);
        short8 a4 = *reinterpret_cast<const short8*>(apt + 2048);
        short8 a5 = *reinterpret_cast<const short8*>(apt + 2560);
        short8 a6 = *reinterpret_cast<const short8*>(apt + 3072);
        short8 a7 = *reinterpret_cast<const short8*>(apt + 3584);

        int labr[8];
        float sqr[8];
        #pragma unroll
        for (int g = 0; g < 2; ++g)
            #pragma unroll
            for (int r = 0; r < 4; ++r) {
                labr[g * 4 + r] = labels[rbase + g * 16 + lq * 4 + r];
                sqr[g * 4 + r]  = sq[rbase + g * 16 + lq * 4 + r];
            }

        colk[tid] = 0; colk[256 + tid] = 0;

        float rmax[8], rmin[8];
        #pragma unroll
        for (int r = 0; r < 8; ++r) { rmax[r] = -INFINITY; rmin[r] = INFINITY; }

        int cbase = chunk * 256;
        const unsigned short* btile = ebf + (cbase >> 4) * 2048 + wave * 512 + lane * 8;
        uint4 bregA = *reinterpret_cast<const uint4*>(btile);           // tile 0
        uint4 bregB = *reinterpret_cast<const uint4*>(btile + 2048);    // tile 1

        for (int it = 0; it < 8; ++it) {
            // stage tiles 2it, 2it+1; prefetch 2it+2, 2it+3
            *reinterpret_cast<uint4*>(&bstage[it & 1][wave * 512 + lane * 8]) = bregA;
            *reinterpret_cast<uint4*>(&bstage[it & 1][2048 + wave * 512 + lane * 8]) = bregB;
            if (it < 7) {
                bregA = *reinterpret_cast<const uint4*>(btile + (2 * it + 2) * 2048);
                bregB = *reinterpret_cast<const uint4*>(btile + (2 * it + 3) * 2048);
            }
            __syncthreads();   // also covers colk init on it=0

            #pragma unroll
            for (int k = 0; k < 2; ++k) {
                int ct = it * 2 + k;
                const unsigned short* bb = &bstage[it & 1][k * 2048 + lane * 8];
                short8 b0 = *reinterpret_cast<const short8*>(bb);
                short8 b1 = *reinterpret_cast<const short8*>(bb + 512);
                short8 b2 = *reinterpret_cast<const short8*>(bb + 1024);
                short8 b3 = *reinterpret_cast<const short8*>(bb + 1536);
                f32x4 c0 = {0.f, 0.f, 0.f, 0.f};
                f32x4 c1 = {0.f, 0.f, 0.f, 0.f};
                c0 = __builtin_amdgcn_mfma_f32_16x16x32_bf16(a0, b0, c0, 0, 0, 0);
                c1 = __builtin_amdgcn_mfma_f32_16x16x32_bf16(a4, b0, c1, 0, 0, 0);
                c0 = __builtin_amdgcn_mfma_f32_16x16x32_bf16(a1, b1, c0, 0, 0, 0);
                c1 = __builtin_amdgcn_mfma_f32_16x16x32_bf16(a5, b1, c1, 0, 0, 0);
                c0 = __builtin_amdgcn_mfma_f32_16x16x32_bf16(a2, b2, c0, 0, 0, 0);
                c1 = __builtin_amdgcn_mfma_f32_16x16x32_bf16(a6, b2, c1, 0, 0, 0);
                c0 = __builtin_amdgcn_mfma_f32_16x16x32_bf16(a3, b3, c0, 0, 0, 0);
                c1 = __builtin_amdgcn_mfma_f32_16x16x32_bf16(a7, b3, c1, 0, 0, 0);

                int col = cbase + ct * 16 + lm;
                float sqc = sq[col];
                int lc = labels[col];
                float cmax = -INFINITY, cmin = INFINITY;
                #pragma unroll
                for (int r = 0; r < 4; ++r) {
                    float v0 = fmaxf(fmaf(c0[r], -2.0f, sqc) + sqr[r], 0.f);
                    bool s0 = (lc == labr[r]);
                    rmax[r] = s0 ? fmaxf(rmax[r], v0) : rmax[r];
                    rmin[r] = s0 ? rmin[r] : fminf(rmin[r], v0);
                    cmax    = s0 ? fmaxf(cmax, v0) : cmax;
                    cmin    = s0 ? cmin : fminf(cmin, v0);
                    float v1 = fmaxf(fmaf(c1[r], -2.0f, sqc) + sqr[4 + r], 0.f);
                    bool s1 = (lc == labr[4 + r]);
                    rmax[4 + r] = s1 ? fmaxf(rmax[4 + r], v1) : rmax[4 + r];
                    rmin[4 + r] = s1 ? rmin[4 + r] : fminf(rmin[4 + r], v1);
                    cmax        = s1 ? fmaxf(cmax, v1) : cmax;
                    cmin        = s1 ? cmin : fminf(cmin, v1);
                }
                cmax = fmaxf(cmax, __shfl_xor(cmax, 16, 64));
                cmax = fmaxf(cmax, __shfl_xor(cmax, 32, 64));
                cmin = fminf(cmin, __shfl_xor(cmin, 16, 64));
                cmin = fminf(cmin, __shfl_xor(cmin, 32, 64));
                if (lq == 0) {
                    atomicMax(&colk[ct * 16 + lm], enc_max(fmaxf(cmax, 0.f)));
                    atomicMax(&colk[256 + ct * 16 + lm], enc_min(fmaxf(cmin, 0.f)));
                }
            }
        }
        // row reduce across the 16 col-slots
        #pragma unroll
        for (int off = 1; off < 16; off <<= 1) {
            #pragma unroll
            for (int r = 0; r < 8; ++r) {
                rmax[r] = fmaxf(rmax[r], __shfl_xor(rmax[r], off, 64));
                rmin[r] = fminf(rmin[r], __shfl_xor(rmin[r], off, 64));
            }
        }
        if (lm == 0) {
            #pragma unroll
            for (int g = 0; g < 2; ++g)
                #pragma unroll
                for (int r = 0; r < 4; ++r) {
                    int row = rbase + g * 16 + lq * 4 + r;
                    unsigned int kx = enc_max(fmaxf(rmax[g * 4 + r], 0.f));
                    unsigned int kn = enc_min(fmaxf(rmin[g * 4 + r], 0.f));
                    if (kx != ENC_MAX_ID)
                        __hip_atomic_fetch_max(&maxk[row], kx,
                                               __ATOMIC_RELAXED, __HIP_MEMORY_SCOPE_AGENT);
                    if (kn != ENC_MIN_ID)
                        __hip_atomic_fetch_max(&mink[row], kn,
                                               __ATOMIC_RELAXED, __HIP_MEMORY_SCOPE_AGENT);
                }
        }
        __syncthreads();
        // column publish: one thread per col
        {
            unsigned int kx = colk[tid], kn = colk[256 + tid];
            int col = cbase + tid;
            if (kx > ENC_MAX_ID)
                __hip_atomic_fetch_max(&maxk[col], kx,
                                       __ATOMIC_RELAXED, __HIP_MEMORY_SCOPE_AGENT);
            if (kn != 0 && kn != ENC_MIN_ID)
                __hip_atomic_fetch_max(&mink[col], kn,
                                       __ATOMIC_RELAXED, __HIP_MEMORY_SCOPE_AGENT);
        }
    }

    // ---------------- CE (blocks 0..255, same block, after pairwise) ----------------
    if (bid < 256) {
        int R0 = bid * 16;
        lg[tid >> 4][112 + (tid & 15)] = -INFINITY;   // pad cols 112..127

        const unsigned short* apt = ebf + (R0 >> 4) * 2048 + lane * 8;
        short8 a0 = *reinterpret_cast<const short8*>(apt);
        short8 a1 = *reinterpret_cast<const short8*>(apt + 512);
        short8 a2 = *reinterpret_cast<const short8*>(apt + 1024);
        short8 a3 = *reinterpret_cast<const short8*>(apt + 1536);

        for (int t = wave * 2; t < 7 && t < wave * 2 + 2; ++t) {
            int cls = t * 16 + lm;
            const unsigned short* bp = wbf + t * 2048 + lane * 8;
            short8 b0 = *reinterpret_cast<const short8*>(bp);
            short8 b1 = *reinterpret_cast<const short8*>(bp + 512);
            short8 b2 = *reinterpret_cast<const short8*>(bp + 1024);
            short8 b3 = *reinterpret_cast<const short8*>(bp + 1536);
            f32x4 c = {0.f, 0.f, 0.f, 0.f};
            c = __builtin_amdgcn_mfma_f32_16x16x32_bf16(a0, b0, c, 0, 0, 0);
            c = __builtin_amdgcn_mfma_f32_16x16x32_bf16(a1, b1, c, 0, 0, 0);
            c = __builtin_amdgcn_mfma_f32_16x16x32_bf16(a2, b2, c, 0, 0, 0);
            c = __builtin_amdgcn_mfma_f32_16x16x32_bf16(a3, b3, c, 0, 0, 0);
            float bias = (cls < NCLS) ? fcb[cls] : -INFINITY;
            #pragma unroll
            for (int r = 0; r < 4; ++r)
                lg[lq * 4 + r][t * 16 + lm] = c[r] + bias;
        }
        __syncthreads();
        float cacc = 0.f;
        #pragma unroll
        for (int i = 0; i < 4; ++i) {
            int r = wave * 4 + i;
            float x0 = lg[r][lane], x1 = lg[r][lane + 64];
            float m = fmaxf(x0, x1);
            #pragma unroll
            for (int off = 1; off < 64; off <<= 1) m = fmaxf(m, __shfl_xor(m, off, 64));
            float s = expf(x0 - m) + expf(x1 - m);    // -inf pads -> 0
            #pragma unroll
            for (int off = 1; off < 64; off <<= 1) s += __shfl_xor(s, off, 64);
            if (lane == 0) {
                int lab = labels[R0 + r];
                cacc += (m + logf(s)) - lg[r][lab];
            }
        }
        __syncthreads();
        if (lane == 0) lg[0][wave] = cacc;
        __syncthreads();
        if (tid == 0) {
            float bsum = lg[0][0] + lg[0][1] + lg[0][2] + lg[0][3];
            __hip_atomic_fetch_add(ce_sum, bsum,
                                   __ATOMIC_RELAXED, __HIP_MEMORY_SCOPE_AGENT);
        }
    }

    // ------- fence-free ticket fan-in -------
    __syncthreads();
    asm volatile("s_waitcnt vmcnt(0)" ::: "memory");
    if (tid == 0) {
        int old = __hip_atomic_fetch_add(ticket, 1,
                                         __ATOMIC_RELAXED, __HIP_MEMORY_SCOPE_AGENT);
        lastFlag = (old == GRID_MAIN - 1);
    }
    __syncthreads();
    if (lastFlag) {
        float acc = 0.f;
        #pragma unroll
        for (int rr = 0; rr < 16; ++rr) {
            int row = rr * 256 + tid;
            unsigned int kx = __hip_atomic_load(&maxk[row], __ATOMIC_RELAXED,
                                                __HIP_MEMORY_SCOPE_AGENT);
            unsigned int kn = __hip_atomic_load(&mink[row], __ATOMIC_RELAXED,
                                                __HIP_MEMORY_SCOPE_AGENT);
            float ap = sqrtf(fmaxf(dec_max(kx), 1e-12f));
            float an = sqrtf(fmaxf(dec_min(kn), 1e-12f));
            acc += fmaxf(ap - an + MARGIN, 0.f);
        }
        float* red = reinterpret_cast<float*>(lg);
        red[tid] = acc;
        __syncthreads();
        for (int s = 128; s > 0; s >>= 1) {
            if (tid < s) red[tid] += red[tid + s];
            __syncthreads();
        }
        if (tid == 0) {
            float ces = __hip_atomic_load(ce_sum, __ATOMIC_RELAXED,
                                          __HIP_MEMORY_SCOPE_AGENT);
            out[0] = (red[0] + ces) * (1.0f / BATCH);
        }
    }
}

extern "C" void kernel_launch(void* const* d_in, const int* in_sizes, int n_in,
                              void* d_out, int out_size, void* d_ws, size_t ws_size,
                              hipStream_t stream) {
    const float* emb    = (const float*)d_in[0];
    const int*   labels = (const int*)  d_in[1];
    const float* fcw    = (const float*)d_in[2];
    const float* fcb    = (const float*)d_in[3];
    float* out = (float*)d_out;

    char* ws = (char*)d_ws;
    unsigned short* ebf = (unsigned short*)(ws);                 // 1 MB (frag-major)
    unsigned short* wbf = (unsigned short*)(ws + 1048576);       // 28 KB (pad 32K)
    float* sq           = (float*)(ws + 1081344);                // 16 KB
    char* fan           = ws + 1097728;                          // zeroed by prep
    int*   ticket       = (int*)(fan);                           // 4 B
    float* ce_sum       = (float*)(fan + 4);                     // 4 B
    unsigned int* maxk  = (unsigned int*)(fan + 8);              // 16 KB
    unsigned int* mink  = (unsigned int*)(fan + 8 + 16384);      // 16 KB

    prep_kernel<<<258, 256, 0, stream>>>(emb, fcw, ebf, sq, wbf,
                                         (unsigned int*)fan);
    main_kernel<<<GRID_MAIN, 256, 0, stream>>>(ebf, wbf, sq, labels, fcb,
                                               maxk, mink, ce_sum, ticket, out);
}

// Round 16
// 94.137 us; speedup vs baseline: 1.0837x; 1.0142x over previous
//
#include <hip/hip_runtime.h>
#include <math.h>

#define BATCH 4096
#define DIM 128
#define NCLS 100
#define MARGIN 0.3f
#define NTILE 272          // upper-triangle 128x256 supertiles
#define GRID_MAIN 528      // 272 pairwise + 256 CE

typedef __attribute__((ext_vector_type(8))) short short8;
typedef __attribute__((ext_vector_type(4))) float f32x4;

// ---- bf16 helpers (bit-level, RNE) ----
__device__ __forceinline__ unsigned short f2bf(float f) {
    unsigned int u = __float_as_uint(f);
    unsigned int r = (u + 0x7FFFu + ((u >> 16) & 1u)) >> 16;
    return (unsigned short)r;
}
__device__ __forceinline__ float bf2f(unsigned short b) {
    return __uint_as_float(((unsigned int)b) << 16);
}

// Order-preserving encodings for NONNEGATIVE floats; identity = 0 under atomic max.
#define ENC_MAX_ID 0x80000000u   /* enc_max(0.0f) */
#define ENC_MIN_ID 0x403FFFFFu   /* enc_min(+inf) */
__device__ __forceinline__ unsigned int enc_max(float v) {
    return (__float_as_uint(v) >> 1) | 0x80000000u;
}
__device__ __forceinline__ float dec_max(unsigned int k) {
    return __uint_as_float((k & 0x7FFFFFFFu) << 1);
}
__device__ __forceinline__ unsigned int enc_min(float v) {
    return 0x7FFFFFFFu - (__float_as_uint(v) >> 1);
}
__device__ __forceinline__ float dec_min(unsigned int k) {
    return __uint_as_float((0x7FFFFFFFu - k) << 1);
}

// FRAGMENT-MAJOR layout: for 16-row group g, element (row%16, dim) lives at
// short-index g*2048 + (dim>>3)*128 + (row%16)*8 + (dim&7). Fragment read j
// for lane l is contiguous: g*2048 + j*512 + l*8 shorts = base + l*16 bytes.

// K1: blocks 0..255: emb->bf16 (frag-major) + sq (from rounded values).
//     blocks 256..257: fc_w->bf16 frag-major (padded to 112 classes) + zero fan-in.
__global__ __launch_bounds__(256) void prep_kernel(
        const float* __restrict__ emb, const float* __restrict__ fcw,
        unsigned short* __restrict__ ebf, float* __restrict__ sq,
        unsigned short* __restrict__ wbf, unsigned int* __restrict__ fanz) {
    int bid = blockIdx.x, tid = threadIdx.x;
    if (bid < 256) {
        int wave = tid >> 6, lane = tid & 63;
        unsigned int* dstg = reinterpret_cast<unsigned int*>(ebf) + bid * 1024;
        #pragma unroll
        for (int r = 0; r < 4; ++r) {
            int rowl = wave * 4 + r;
            int row = bid * 16 + rowl;
            const float2* src = reinterpret_cast<const float2*>(emb + row * DIM);
            float2 xy = src[lane];
            unsigned short b0 = f2bf(xy.x), b1 = f2bf(xy.y);
            float y0 = bf2f(b0), y1 = bf2f(b1);
            dstg[(lane >> 2) * 64 + rowl * 4 + (lane & 3)] =
                ((unsigned int)b1 << 16) | (unsigned int)b0;
            float acc = y0 * y0 + y1 * y1;
            #pragma unroll
            for (int off = 1; off < 64; off <<= 1) acc += __shfl_xor(acc, off, 64);
            if (lane == 0) sq[row] = acc;
        }
    } else {
        int idx = (bid - 256) * 256 + tid;          // 512 threads total
        for (int k = idx; k < 112 * DIM; k += 512) {
            int cls = k >> 7, d = k & 127;
            int dst = (cls >> 4) * 2048 + (d >> 3) * 128 + (cls & 15) * 8 + (d & 7);
            wbf[dst] = (k < NCLS * DIM) ? f2bf(fcw[k]) : (unsigned short)0;
        }
        for (int w = idx; w < 8194; w += 512)       // ticket+ce_sum+maxk+mink
            fanz[w] = 0;
    }
}

// K2: blocks 0..271  -> upper-triangle 128x256 supertiles, DOUBLE-BUFFERED LDS
//                       B-staging (block stages each 4KB B-tile ONCE; waves
//                       read fragments via ds_read_b128; global B-instrs /4);
//     blocks 272..527 -> CE per 16 rows via MFMA logits + wave softmax.
//     Fence-free encoded-atomic fan-in; last block reduces + writes out[0].
__global__ __launch_bounds__(256) void main_kernel(
        const unsigned short* __restrict__ ebf, const unsigned short* __restrict__ wbf,
        const float* __restrict__ sq, const int* __restrict__ labels,
        const float* __restrict__ fcb,
        unsigned int* __restrict__ maxk, unsigned int* __restrict__ mink,
        float* __restrict__ ce_sum, int* __restrict__ ticket,
        float* __restrict__ out) {
    __shared__ float lg[16][128];
    __shared__ unsigned int colk[512];   // [0..255] col-max keys, [256..511] col-min keys
    __shared__ unsigned short bstage[2][2048];   // 2 x 4KB B-tiles
    __shared__ int lastFlag;
    int bid = blockIdx.x, tid = threadIdx.x;
    int wave = tid >> 6, lane = tid & 63;
    int lm = lane & 15, lq = lane >> 4;

    if (bid < NTILE) {
        // ---- map bid -> (rowgrp, chunk): chunk c admits rowgrps 0..2c+1 ----
        int c = 0, rem = bid;
        while (rem >= 2 * c + 2) { rem -= 2 * c + 2; ++c; }
        int rowgrp = rem, chunk = c;

        int rbase = rowgrp * 128 + wave * 32;   // this wave's 32 rows
        const unsigned short* apt = ebf + (rbase >> 4) * 2048 + lane * 8;
        short8 a0 = *reinterpret_cast<const short8*>(apt);
        short8 a1 = *reinterpret_cast<const short8*>(apt + 512);
        short8 a2 = *reinterpret_cast<const short8*>(apt + 1024);
        short8 a3 = *reinterpret_cast<const short8*>(apt + 1536);
        short8 a4 = *reinterpret_cast<const short8*>(apt + 2048);
        short8 a5 = *reinterpret_cast<const short8*>(apt + 2560);
        short8 a6 = *reinterpret_cast<const short8*>(apt + 3072);
        short8 a7 = *reinterpret_cast<const short8*>(apt + 3584);

        int labr[8];
        float sqr[8];
        #pragma unroll
        for (int g = 0; g < 2; ++g)
            #pragma unroll
            for (int r = 0; r < 4; ++r) {
                labr[g * 4 + r] = labels[rbase + g * 16 + lq * 4 + r];
                sqr[g * 4 + r]  = sq[rbase + g * 16 + lq * 4 + r];
            }

        colk[tid] = 0; colk[256 + tid] = 0;

        float rmax[8], rmin[8];
        #pragma unroll
        for (int r = 0; r < 8; ++r) { rmax[r] = -INFINITY; rmin[r] = INFINITY; }

        int cbase = chunk * 256;
        // B-tile ct occupies shorts [ct*2048, (ct+1)*2048) of the chunk's region.
        // This wave stages quarter `wave`: 64 lanes x 16B = 1024B.
        const unsigned short* btile = ebf + (cbase >> 4) * 2048 + wave * 512 + lane * 8;
        uint4 breg = *reinterpret_cast<const uint4*>(btile);   // tile 0

        for (int ct = 0; ct < 16; ++ct) {
            // write tile ct to LDS buffer, prefetch tile ct+1 into regs
            *reinterpret_cast<uint4*>(&bstage[ct & 1][wave * 512 + lane * 8]) = breg;
            if (ct < 15)
                breg = *reinterpret_cast<const uint4*>(btile + (ct + 1) * 2048);
            __syncthreads();   // also covers colk init on ct=0

            const unsigned short* bb = &bstage[ct & 1][lane * 8];
            short8 b0 = *reinterpret_cast<const short8*>(bb);
            short8 b1 = *reinterpret_cast<const short8*>(bb + 512);
            short8 b2 = *reinterpret_cast<const short8*>(bb + 1024);
            short8 b3 = *reinterpret_cast<const short8*>(bb + 1536);
            // two independent MFMA chains (row-groups 0 and 1)
            f32x4 c0 = {0.f, 0.f, 0.f, 0.f};
            f32x4 c1 = {0.f, 0.f, 0.f, 0.f};
            c0 = __builtin_amdgcn_mfma_f32_16x16x32_bf16(a0, b0, c0, 0, 0, 0);
            c1 = __builtin_amdgcn_mfma_f32_16x16x32_bf16(a4, b0, c1, 0, 0, 0);
            c0 = __builtin_amdgcn_mfma_f32_16x16x32_bf16(a1, b1, c0, 0, 0, 0);
            c1 = __builtin_amdgcn_mfma_f32_16x16x32_bf16(a5, b1, c1, 0, 0, 0);
            c0 = __builtin_amdgcn_mfma_f32_16x16x32_bf16(a2, b2, c0, 0, 0, 0);
            c1 = __builtin_amdgcn_mfma_f32_16x16x32_bf16(a6, b2, c1, 0, 0, 0);
            c0 = __builtin_amdgcn_mfma_f32_16x16x32_bf16(a3, b3, c0, 0, 0, 0);
            c1 = __builtin_amdgcn_mfma_f32_16x16x32_bf16(a7, b3, c1, 0, 0, 0);

            int col = cbase + ct * 16 + lm;
            float sqc = sq[col];
            int lc = labels[col];
            float cmax = -INFINITY, cmin = INFINITY;
            #pragma unroll
            for (int r = 0; r < 4; ++r) {
                float v0 = fmaxf(fmaf(c0[r], -2.0f, sqc) + sqr[r], 0.f);
                bool s0 = (lc == labr[r]);
                rmax[r] = s0 ? fmaxf(rmax[r], v0) : rmax[r];
                rmin[r] = s0 ? rmin[r] : fminf(rmin[r], v0);
                cmax    = s0 ? fmaxf(cmax, v0) : cmax;
                cmin    = s0 ? cmin : fminf(cmin, v0);
                float v1 = fmaxf(fmaf(c1[r], -2.0f, sqc) + sqr[4 + r], 0.f);
                bool s1 = (lc == labr[4 + r]);
                rmax[4 + r] = s1 ? fmaxf(rmax[4 + r], v1) : rmax[4 + r];
                rmin[4 + r] = s1 ? rmin[4 + r] : fminf(rmin[4 + r], v1);
                cmax        = s1 ? fmaxf(cmax, v1) : cmax;
                cmin        = s1 ? cmin : fminf(cmin, v1);
            }
            // fold this wave's 32 rows into the 16 cols (combine lq groups)
            cmax = fmaxf(cmax, __shfl_xor(cmax, 16, 64));
            cmax = fmaxf(cmax, __shfl_xor(cmax, 32, 64));
            cmin = fminf(cmin, __shfl_xor(cmin, 16, 64));
            cmin = fminf(cmin, __shfl_xor(cmin, 32, 64));
            if (lq == 0) {   // 16 lanes, 16 distinct banks -> conflict-free ds atomics
                atomicMax(&colk[ct * 16 + lm], enc_max(fmaxf(cmax, 0.f)));
                atomicMax(&colk[256 + ct * 16 + lm], enc_min(fmaxf(cmin, 0.f)));
            }
        }
        // row reduce across the 16 col-slots
        #pragma unroll
        for (int off = 1; off < 16; off <<= 1) {
            #pragma unroll
            for (int r = 0; r < 8; ++r) {
                rmax[r] = fmaxf(rmax[r], __shfl_xor(rmax[r], off, 64));
                rmin[r] = fminf(rmin[r], __shfl_xor(rmin[r], off, 64));
            }
        }
        if (lm == 0) {
            #pragma unroll
            for (int g = 0; g < 2; ++g)
                #pragma unroll
                for (int r = 0; r < 4; ++r) {
                    int row = rbase + g * 16 + lq * 4 + r;
                    unsigned int kx = enc_max(fmaxf(rmax[g * 4 + r], 0.f));
                    unsigned int kn = enc_min(fmaxf(rmin[g * 4 + r], 0.f));
                    if (kx != ENC_MAX_ID)
                        __hip_atomic_fetch_max(&maxk[row], kx,
                                               __ATOMIC_RELAXED, __HIP_MEMORY_SCOPE_AGENT);
                    if (kn != ENC_MIN_ID)
                        __hip_atomic_fetch_max(&mink[row], kn,
                                               __ATOMIC_RELAXED, __HIP_MEMORY_SCOPE_AGENT);
                }
        }
        __syncthreads();
        // column publish: one thread per col
        {
            unsigned int kx = colk[tid], kn = colk[256 + tid];
            int col = cbase + tid;
            if (kx > ENC_MAX_ID)       // >: skip identity AND the harmless enc_max(0)
                __hip_atomic_fetch_max(&maxk[col], kx,
                                       __ATOMIC_RELAXED, __HIP_MEMORY_SCOPE_AGENT);
            if (kn != 0 && kn != ENC_MIN_ID)
                __hip_atomic_fetch_max(&mink[col], kn,
                                       __ATOMIC_RELAXED, __HIP_MEMORY_SCOPE_AGENT);
        }
    } else {
        // ---------------- cross-entropy ----------------
        int R0 = (bid - NTILE) * 16;
        lg[tid >> 4][112 + (tid & 15)] = -INFINITY;   // pad cols 112..127

        const unsigned short* apt = ebf + (R0 >> 4) * 2048 + lane * 8;
        short8 a0 = *reinterpret_cast<const short8*>(apt);
        short8 a1 = *reinterpret_cast<const short8*>(apt + 512);
        short8 a2 = *reinterpret_cast<const short8*>(apt + 1024);
        short8 a3 = *reinterpret_cast<const short8*>(apt + 1536);

        for (int t = wave * 2; t < 7 && t < wave * 2 + 2; ++t) {
            int cls = t * 16 + lm;
            const unsigned short* bp = wbf + t * 2048 + lane * 8;
            short8 b0 = *reinterpret_cast<const short8*>(bp);
            short8 b1 = *reinterpret_cast<const short8*>(bp + 512);
            short8 b2 = *reinterpret_cast<const short8*>(bp + 1024);
            short8 b3 = *reinterpret_cast<const short8*>(bp + 1536);
            f32x4 c = {0.f, 0.f, 0.f, 0.f};
            c = __builtin_amdgcn_mfma_f32_16x16x32_bf16(a0, b0, c, 0, 0, 0);
            c = __builtin_amdgcn_mfma_f32_16x16x32_bf16(a1, b1, c, 0, 0, 0);
            c = __builtin_amdgcn_mfma_f32_16x16x32_bf16(a2, b2, c, 0, 0, 0);
            c = __builtin_amdgcn_mfma_f32_16x16x32_bf16(a3, b3, c, 0, 0, 0);
            float bias = (cls < NCLS) ? fcb[cls] : -INFINITY;
            #pragma unroll
            for (int r = 0; r < 4; ++r)
                lg[lq * 4 + r][t * 16 + lm] = c[r] + bias;
        }
        __syncthreads();
        float cacc = 0.f;
        #pragma unroll
        for (int i = 0; i < 4; ++i) {
            int r = wave * 4 + i;
            float x0 = lg[r][lane], x1 = lg[r][lane + 64];
            float m = fmaxf(x0, x1);
            #pragma unroll
            for (int off = 1; off < 64; off <<= 1) m = fmaxf(m, __shfl_xor(m, off, 64));
            float s = expf(x0 - m) + expf(x1 - m);    // -inf pads -> 0
            #pragma unroll
            for (int off = 1; off < 64; off <<= 1) s += __shfl_xor(s, off, 64);
            if (lane == 0) {
                int lab = labels[R0 + r];
                cacc += (m + logf(s)) - lg[r][lab];
            }
        }
        __syncthreads();
        if (lane == 0) lg[0][wave] = cacc;
        __syncthreads();
        if (tid == 0) {
            float bsum = lg[0][0] + lg[0][1] + lg[0][2] + lg[0][3];
            __hip_atomic_fetch_add(ce_sum, bsum,
                                   __ATOMIC_RELAXED, __HIP_MEMORY_SCOPE_AGENT);
        }
    }

    // ------- fence-free ticket fan-in -------
    __syncthreads();
    asm volatile("s_waitcnt vmcnt(0)" ::: "memory");
    if (tid == 0) {
        int old = __hip_atomic_fetch_add(ticket, 1,
                                         __ATOMIC_RELAXED, __HIP_MEMORY_SCOPE_AGENT);
        lastFlag = (old == GRID_MAIN - 1);
    }
    __syncthreads();
    if (lastFlag) {
        float acc = 0.f;
        #pragma unroll
        for (int rr = 0; rr < 16; ++rr) {
            int row = rr * 256 + tid;
            unsigned int kx = __hip_atomic_load(&maxk[row], __ATOMIC_RELAXED,
                                                __HIP_MEMORY_SCOPE_AGENT);
            unsigned int kn = __hip_atomic_load(&mink[row], __ATOMIC_RELAXED,
                                                __HIP_MEMORY_SCOPE_AGENT);
            float ap = sqrtf(fmaxf(dec_max(kx), 1e-12f));
            float an = sqrtf(fmaxf(dec_min(kn), 1e-12f));
            acc += fmaxf(ap - an + MARGIN, 0.f);
        }
        float* red = reinterpret_cast<float*>(lg);
        red[tid] = acc;
        __syncthreads();
        for (int s = 128; s > 0; s >>= 1) {
            if (tid < s) red[tid] += red[tid + s];
            __syncthreads();
        }
        if (tid == 0) {
            float ces = __hip_atomic_load(ce_sum, __ATOMIC_RELAXED,
                                          __HIP_MEMORY_SCOPE_AGENT);
            out[0] = (red[0] + ces) * (1.0f / BATCH);
        }
    }
}

extern "C" void kernel_launch(void* const* d_in, const int* in_sizes, int n_in,
                              void* d_out, int out_size, void* d_ws, size_t ws_size,
                              hipStream_t stream) {
    const float* emb    = (const float*)d_in[0];
    const int*   labels = (const int*)  d_in[1];
    const float* fcw    = (const float*)d_in[2];
    const float* fcb    = (const float*)d_in[3];
    float* out = (float*)d_out;

    char* ws = (char*)d_ws;
    unsigned short* ebf = (unsigned short*)(ws);                 // 1 MB (frag-major)
    unsigned short* wbf = (unsigned short*)(ws + 1048576);       // 28 KB (pad 32K)
    float* sq           = (float*)(ws + 1081344);                // 16 KB
    char* fan           = ws + 1097728;                          // zeroed by prep
    int*   ticket       = (int*)(fan);                           // 4 B
    float* ce_sum       = (float*)(fan + 4);                     // 4 B
    unsigned int* maxk  = (unsigned int*)(fan + 8);              // 16 KB
    unsigned int* mink  = (unsigned int*)(fan + 8 + 16384);      // 16 KB

    prep_kernel<<<258, 256, 0, stream>>>(emb, fcw, ebf, sq, wbf,
                                         (unsigned int*)fan);
    main_kernel<<<GRID_MAIN, 256, 0, stream>>>(ebf, wbf, sq, labels, fcb,
                                               maxk, mink, ce_sum, ticket, out);
}